// Round 3
// baseline (732.831 us; speedup 1.0000x reference)
//
#include <hip/hip_runtime.h>

typedef _Float16 half8 __attribute__((ext_vector_type(8)));
typedef float f32x4 __attribute__((ext_vector_type(4)));

#define LOG2E 1.44269504088896340736f

// B=64, T=512, S=1024. GEMM: [B*S, T] x [T, T], fused mask/tanh/softmax/reduce.

// ---------------- W pack kernel ----------------
// Packs W [512 t][512 u] f32 row-major into an f16 LDS-image for the B operand.
// Per k-step ks (32 k values): 2048 chunks of 16B. Chunk c holds:
//   n  = c>>2, kb = (c&3) ^ (n&3)   (XOR swizzle for bank-spread reads)
//   elems j=0..7 -> W[ks*32 + kb*8 + j][n]
__global__ void pack_w_kernel(const float* __restrict__ W, _Float16* __restrict__ wp) {
    int id = blockIdx.x * 256 + threadIdx.x;   // 0 .. 262143
    int ks = id >> 14;
    int r  = id & 16383;
    int c  = r >> 3;
    int j  = r & 7;
    int n  = c >> 2;
    int kb = (c & 3) ^ (n & 3);
    int k  = ks * 32 + kb * 8 + j;
    wp[id] = (_Float16)W[k * 512 + n];
}

// ---------------- fused main kernel ----------------
// grid: 2048 blocks = 64 b * 32 s-tiles (32 rows each). 256 threads = 4 waves.
// LDS: sA = v-tile [32 m(s)][512 k(t)] f16, XOR-swizzled chunks; sW = W k-step tile.
__global__ __launch_bounds__(256, 2)
void attn_fused_kernel(const float* __restrict__ x, const int* __restrict__ mask,
                       const float* __restrict__ Wraw, const _Float16* __restrict__ wp,
                       const float* __restrict__ bias, float* __restrict__ out,
                       int use_packed) {
    __shared__ char sA[32768];
    __shared__ char sW[32768];

    const int tid  = threadIdx.x;
    const int lane = tid & 63;
    const int w    = tid >> 6;          // wave 0..3, owns n in [w*128, w*128+128)
    const int bid  = blockIdx.x;
    const int b    = bid >> 5;
    const int s0   = (bid & 31) * 32;
    const size_t xbase = (size_t)b * 512 * 1024;

    // ---- Stage A: v[m=s][k=t] = x[b][t][s0+m] * mask, f16, swizzled ----
    // Layout: byte = m*1024 + ((((t>>3) ^ m) & 63) << 4) + (t&7)*2
    {
        const int sAi = lane & 31;      // m
        const int p   = lane >> 5;      // row-pair select
        #pragma unroll 4
        for (int it = 0; it < 32; ++it) {
            int t0 = w * 128 + it * 4 + p * 2;          // even
            size_t g0 = xbase + (size_t)t0 * 1024 + s0 + sAi;
            float v0 = mask[g0]        ? x[g0]        : 0.0f;
            float v1 = mask[g0 + 1024] ? x[g0 + 1024] : 0.0f;
            _Float16 h0 = (_Float16)v0, h1 = (_Float16)v1;
            unsigned short u0, u1;
            __builtin_memcpy(&u0, &h0, 2);
            __builtin_memcpy(&u1, &h1, 2);
            unsigned pk = (unsigned)u0 | ((unsigned)u1 << 16);
            int byteoff = sAi * 1024 + ((((t0 >> 3) ^ sAi) & 63) << 4) + (t0 & 7) * 2;
            *((unsigned*)&sA[byteoff]) = pk;
        }
    }

    // ---- K loop: 16 steps of k=32 ----
    f32x4 acc[2][8];
    #pragma unroll
    for (int i = 0; i < 2; ++i)
        #pragma unroll
        for (int j2 = 0; j2 < 8; ++j2)
            acc[i][j2] = (f32x4){0.f, 0.f, 0.f, 0.f};

    const uint4* wp4 = (const uint4*)wp;
    uint4 wreg[8];
    if (use_packed) {
        #pragma unroll
        for (int c = 0; c < 8; ++c)
            wreg[c] = wp4[w * 512 + c * 64 + lane];
    }

    for (int ks = 0; ks < 16; ++ks) {
        __syncthreads();   // previous tile's reads complete / A-tile ready
        if (use_packed) {
            #pragma unroll
            for (int c = 0; c < 8; ++c)
                *((uint4*)&sW[(w * 512 + c * 64 + lane) * 16]) = wreg[c];
        } else {
            // fallback: stage from raw f32 W (coalesced read, scalar scatter write)
            #pragma unroll 4
            for (int rep = 0; rep < 64; ++rep) {
                int id = rep * 256 + tid;
                int n = id & 511, kk = id >> 9;
                float wv = Wraw[(size_t)(ks * 32 + kk) * 512 + n];
                _Float16 h = (_Float16)wv;
                int byteoff = (n * 4 + ((kk >> 3) ^ (n & 3))) * 16 + (kk & 7) * 2;
                *((_Float16*)&sW[byteoff]) = h;
            }
        }
        __syncthreads();   // tile ready
        if (use_packed && ks < 15) {
            #pragma unroll
            for (int c = 0; c < 8; ++c)
                wreg[c] = wp4[(ks + 1) * 2048 + w * 512 + c * 64 + lane];
        }

        // A fragments: lane -> A[row = mf*16 + (lane&15)][k = ks*32 + (lane>>4)*8 + j]
        half8 aF[2];
        #pragma unroll
        for (int mf = 0; mf < 2; ++mf) {
            int mA = mf * 16 + (lane & 15);
            int byteoff = mA * 1024 + (((ks * 4 + (lane >> 4)) ^ mA) << 4);
            aF[mf] = *((const half8*)&sA[byteoff]);
        }
        // B fragments + MFMA
        #pragma unroll
        for (int nf = 0; nf < 8; ++nf) {
            int n = w * 128 + nf * 16 + (lane & 15);
            int cchunk = n * 4 + ((lane >> 4) ^ (n & 3));
            half8 bF = *((const half8*)&sW[cchunk * 16]);
            acc[0][nf] = __builtin_amdgcn_mfma_f32_16x16x32_f16(aF[0], bF, acc[0][nf], 0, 0, 0);
            acc[1][nf] = __builtin_amdgcn_mfma_f32_16x16x32_f16(aF[1], bF, acc[1][nf], 0, 0, 0);
        }
    }

    // ---- Epilogue ----
    // acc[mf][nf][r] = z_pre[row = mf*16 + (lane>>4)*4 + r][n = w*128 + nf*16 + (lane&15)]
    float bb[8];
    #pragma unroll
    for (int nf = 0; nf < 8; ++nf)
        bb[nf] = bias[w * 128 + nf * 16 + (lane & 15)];

    float rs[2][4] = {};
    #pragma unroll
    for (int mf = 0; mf < 2; ++mf)
        #pragma unroll
        for (int nf = 0; nf < 8; ++nf)
            #pragma unroll
            for (int r = 0; r < 4; ++r) {
                float z = acc[mf][nf][r] + bb[nf];
                // tanh(z) = 1 - 2/(1+e^{2z}); saturates correctly at +/-inf
                float u = __builtin_amdgcn_exp2f(z * (2.0f * LOG2E));
                float t = 1.0f - 2.0f * __builtin_amdgcn_rcpf(1.0f + u);
                float e = __builtin_amdgcn_exp2f(t * LOG2E);
                acc[mf][nf][r] = e;
                rs[mf][r] += e;
            }
    // reduce e over the 16 col-lanes (same lane>>4 group)
    #pragma unroll
    for (int mf = 0; mf < 2; ++mf)
        #pragma unroll
        for (int r = 0; r < 4; ++r) {
            float v = rs[mf][r];
            v += __shfl_xor(v, 1);
            v += __shfl_xor(v, 2);
            v += __shfl_xor(v, 4);
            v += __shfl_xor(v, 8);
            rs[mf][r] = v;   // partial row-sum over this wave's 128 cols
        }
    __syncthreads();                  // all waves done reading sW -> reuse as scratch
    float* sc = (float*)sW;           // scratch [32 rows][4 waves]
    if ((lane & 15) == 0) {
        #pragma unroll
        for (int mf = 0; mf < 2; ++mf)
            #pragma unroll
            for (int r = 0; r < 4; ++r)
                sc[(mf * 16 + (lane >> 4) * 4 + r) * 4 + w] = rs[mf][r];
    }
    __syncthreads();
    float rcpden[2][4];
    #pragma unroll
    for (int mf = 0; mf < 2; ++mf)
        #pragma unroll
        for (int r = 0; r < 4; ++r) {
            int row = mf * 16 + (lane >> 4) * 4 + r;
            float d = sc[row * 4 + 0] + sc[row * 4 + 1] + sc[row * 4 + 2] + sc[row * 4 + 3] + 1e-7f;
            rcpden[mf][r] = __builtin_amdgcn_rcpf(d);
        }
    // out[b][n] += sum_rows att * v[row][n]   (v re-read from resident sA)
    #pragma unroll
    for (int nf = 0; nf < 8; ++nf) {
        int n = w * 128 + nf * 16 + (lane & 15);
        float cs = 0.f;
        #pragma unroll
        for (int mf = 0; mf < 2; ++mf)
            #pragma unroll
            for (int r = 0; r < 4; ++r) {
                int row = mf * 16 + (lane >> 4) * 4 + r;
                float att = acc[mf][nf][r] * rcpden[mf][r];
                int byteoff = row * 1024 + ((((n >> 3) ^ row) & 63) << 4) + (n & 7) * 2;
                _Float16 hv = *((const _Float16*)&sA[byteoff]);
                cs += att * (float)hv;
            }
        cs += __shfl_xor(cs, 16);
        cs += __shfl_xor(cs, 32);
        if (lane < 16) atomicAdd(&out[b * 512 + n], cs);
    }
}

extern "C" void kernel_launch(void* const* d_in, const int* in_sizes, int n_in,
                              void* d_out, int out_size, void* d_ws, size_t ws_size,
                              hipStream_t stream) {
    const float* x    = (const float*)d_in[0];
    const int*   mask = (const int*)d_in[1];
    const float* W    = (const float*)d_in[2];
    const float* bias = (const float*)d_in[3];
    float* out = (float*)d_out;

    hipMemsetAsync(d_out, 0, (size_t)out_size * sizeof(float), stream);

    int use_packed = (ws_size >= (size_t)524288) ? 1 : 0;
    _Float16* wp = (_Float16*)d_ws;
    if (use_packed) {
        pack_w_kernel<<<1024, 256, 0, stream>>>(W, wp);
    }
    attn_fused_kernel<<<2048, 256, 0, stream>>>(x, mask, W, wp, bias, out, use_packed);
}

// Round 4
// 345.138 us; speedup vs baseline: 2.1233x; 2.1233x over previous
//
#include <hip/hip_runtime.h>

typedef _Float16 half8 __attribute__((ext_vector_type(8)));
typedef float f32x4 __attribute__((ext_vector_type(4)));

#define LOG2E 1.44269504088896340736f

// B=64, T=512, S=1024. GEMM: [B*S, T] x [T, T], fused mask/tanh/softmax/reduce.

// async global->LDS, 16B per lane, dest = wave-uniform base + lane*16
__device__ __forceinline__ void gll16(const void* g, void* l) {
    __builtin_amdgcn_global_load_lds(
        (const __attribute__((address_space(1))) unsigned int*)g,
        (__attribute__((address_space(3))) unsigned int*)l,
        16, 0, 0);
}

// ---------------- W pack kernel (LDS-tiled, coalesced both sides) ----------------
// wp chunk c (16B) within ks-slab: n = c>>2, q = c&3, kb = q ^ (n&3),
//   elems j=0..7 -> W[ks*32 + kb*8 + j][n]
__global__ __launch_bounds__(256) void pack_w_kernel(const float* __restrict__ W,
                                                     uint4* __restrict__ wp) {
    __shared__ _Float16 sw[32][128];
    const int ks = blockIdx.x >> 2;        // 0..15
    const int nb = blockIdx.x & 3;         // 128-col group
    const int tid = threadIdx.x;
    #pragma unroll
    for (int rep = 0; rep < 16; ++rep) {
        int idx = rep * 256 + tid;         // 0..4095
        int k = idx >> 7, n = idx & 127;
        sw[k][n] = (_Float16)W[(size_t)(ks * 32 + k) * 512 + nb * 128 + n];
    }
    __syncthreads();
    #pragma unroll
    for (int rep = 0; rep < 2; ++rep) {
        int ci = rep * 256 + tid;          // local chunk 0..511
        int nloc = ci >> 2, q = ci & 3;
        int n = nb * 128 + nloc;
        int kb = q ^ (n & 3);
        union { _Float16 h[8]; uint4 u; } pk;
        #pragma unroll
        for (int j = 0; j < 8; ++j) pk.h[j] = sw[kb * 8 + j][nloc];
        wp[ks * 2048 + n * 4 + q] = pk.u;
    }
}

// ---------------- fused main kernel ----------------
// grid: 2048 blocks = 64 b * 32 s-tiles (32 rows each). 256 threads = 4 waves.
// LDS: sA = v-tile [32 m(s)][512 k(t)] f16 (XOR-swizzled chunks), whole-K resident;
//      sW = W k-step tile (32k x 512n), staged via global_load_lds from packed image.
template <int USE_PACKED>
__global__ __launch_bounds__(256, 2)
void attn_fused_kernel(const float* __restrict__ x, const int* __restrict__ mask,
                       const float* __restrict__ Wraw, const uint4* __restrict__ wp4,
                       const float* __restrict__ bias, float* __restrict__ out) {
    __shared__ char sA[32768];
    __shared__ char sW[32768];

    const int tid  = threadIdx.x;
    const int lane = tid & 63;
    const int w    = tid >> 6;          // wave 0..3, owns n in [w*128, w*128+128)
    const int bid  = blockIdx.x;
    const int b    = bid >> 5;
    const int s0   = (bid & 31) * 32;
    const size_t xbase = (size_t)b * 512 * 1024;

    // ---- Stage A: v[m=s][k=t] = x[b][t][s0+m] * mask, f16, swizzled ----
    // Layout: byte = m*1024 + ((((t>>3) ^ m) & 63) << 4) + (t&7)*2
    {
        const int sAi = lane & 31;      // m
        const int p   = lane >> 5;      // row-pair select
        #pragma unroll 8
        for (int it = 0; it < 32; ++it) {
            int t0 = w * 128 + it * 4 + p * 2;          // even
            size_t g0 = xbase + (size_t)t0 * 1024 + s0 + sAi;
            // explicit independent loads (no mask->x dependence chain)
            float xv0 = x[g0];
            float xv1 = x[g0 + 1024];
            int   mv0 = mask[g0];
            int   mv1 = mask[g0 + 1024];
            float v0 = mv0 ? xv0 : 0.0f;
            float v1 = mv1 ? xv1 : 0.0f;
            _Float16 h0 = (_Float16)v0, h1 = (_Float16)v1;
            unsigned short u0, u1;
            __builtin_memcpy(&u0, &h0, 2);
            __builtin_memcpy(&u1, &h1, 2);
            unsigned pk = (unsigned)u0 | ((unsigned)u1 << 16);
            int byteoff = sAi * 1024 + ((((t0 >> 3) ^ sAi) & 63) << 4) + (t0 & 7) * 2;
            *((unsigned*)&sA[byteoff]) = pk;
        }
    }

    // ---- K loop: 16 steps of k=32 ----
    f32x4 acc[2][8];
    #pragma unroll
    for (int i = 0; i < 2; ++i)
        #pragma unroll
        for (int j2 = 0; j2 < 8; ++j2)
            acc[i][j2] = (f32x4){0.f, 0.f, 0.f, 0.f};

    for (int ks = 0; ks < 16; ++ks) {
        __syncthreads();   // all waves done reading sW (prev iter) / sA staged
        if constexpr (USE_PACKED) {
            // 8 x 16B-per-lane async copies; LDS dest = uniform base + lane*16,
            // matching packed chunk order exactly.
            const uint4* src = wp4 + ks * 2048 + w * 512 + lane;
            char* dst = &sW[w * 8192];
            #pragma unroll
            for (int c = 0; c < 8; ++c)
                gll16(src + c * 64, dst + c * 1024);
        } else {
            // fallback: stage from raw f32 W (coalesced read, scalar scatter write)
            #pragma unroll 4
            for (int rep = 0; rep < 64; ++rep) {
                int id = rep * 256 + tid;
                int n = id & 511, kk = id >> 9;
                float wv = Wraw[(size_t)(ks * 32 + kk) * 512 + n];
                _Float16 h = (_Float16)wv;
                int byteoff = (n * 4 + ((kk >> 3) ^ (n & 3))) * 16 + (kk & 7) * 2;
                *((_Float16*)&sW[byteoff]) = h;
            }
        }
        __syncthreads();   // vmcnt(0)+lgkmcnt(0) drained by barrier -> tile ready

        // A fragments: lane -> A[row = mf*16 + (lane&15)][k = ks*32 + (lane>>4)*8 + j]
        half8 aF[2];
        #pragma unroll
        for (int mf = 0; mf < 2; ++mf) {
            int mA = mf * 16 + (lane & 15);
            int byteoff = mA * 1024 + (((ks * 4 + (lane >> 4)) ^ mA) << 4);
            aF[mf] = *((const half8*)&sA[byteoff]);
        }
        // B fragments + MFMA
        #pragma unroll
        for (int nf = 0; nf < 8; ++nf) {
            int n = w * 128 + nf * 16 + (lane & 15);
            int cchunk = n * 4 + ((lane >> 4) ^ (n & 3));
            half8 bF = *((const half8*)&sW[cchunk * 16]);
            acc[0][nf] = __builtin_amdgcn_mfma_f32_16x16x32_f16(aF[0], bF, acc[0][nf], 0, 0, 0);
            acc[1][nf] = __builtin_amdgcn_mfma_f32_16x16x32_f16(aF[1], bF, acc[1][nf], 0, 0, 0);
        }
    }

    // ---- Epilogue ----
    // acc[mf][nf][r] = z_pre[row = mf*16 + (lane>>4)*4 + r][n = w*128 + nf*16 + (lane&15)]
    float bb[8];
    #pragma unroll
    for (int nf = 0; nf < 8; ++nf)
        bb[nf] = bias[w * 128 + nf * 16 + (lane & 15)];

    float rs[2][4] = {};
    #pragma unroll
    for (int mf = 0; mf < 2; ++mf)
        #pragma unroll
        for (int nf = 0; nf < 8; ++nf)
            #pragma unroll
            for (int r = 0; r < 4; ++r) {
                float z = acc[mf][nf][r] + bb[nf];
                // tanh(z) = 1 - 2/(1+e^{2z}); saturates correctly at +/-inf
                float u = __builtin_amdgcn_exp2f(z * (2.0f * LOG2E));
                float t = 1.0f - 2.0f * __builtin_amdgcn_rcpf(1.0f + u);
                float e = __builtin_amdgcn_exp2f(t * LOG2E);
                acc[mf][nf][r] = e;
                rs[mf][r] += e;
            }
    // reduce e over the 16 col-lanes (same lane>>4 group)
    #pragma unroll
    for (int mf = 0; mf < 2; ++mf)
        #pragma unroll
        for (int r = 0; r < 4; ++r) {
            float v = rs[mf][r];
            v += __shfl_xor(v, 1);
            v += __shfl_xor(v, 2);
            v += __shfl_xor(v, 4);
            v += __shfl_xor(v, 8);
            rs[mf][r] = v;   // partial row-sum over this wave's 128 cols
        }
    __syncthreads();                  // all waves done reading sW -> reuse as scratch
    float* sc = (float*)sW;           // scratch [32 rows][4 waves]
    if ((lane & 15) == 0) {
        #pragma unroll
        for (int mf = 0; mf < 2; ++mf)
            #pragma unroll
            for (int r = 0; r < 4; ++r)
                sc[(mf * 16 + (lane >> 4) * 4 + r) * 4 + w] = rs[mf][r];
    }
    __syncthreads();
    float rcpden[2][4];
    #pragma unroll
    for (int mf = 0; mf < 2; ++mf)
        #pragma unroll
        for (int r = 0; r < 4; ++r) {
            int row = mf * 16 + (lane >> 4) * 4 + r;
            float d = sc[row * 4 + 0] + sc[row * 4 + 1] + sc[row * 4 + 2] + sc[row * 4 + 3] + 1e-7f;
            rcpden[mf][r] = __builtin_amdgcn_rcpf(d);
        }
    // out[b][n] += sum_rows att * v[row][n]   (v re-read from resident sA)
    #pragma unroll
    for (int nf = 0; nf < 8; ++nf) {
        int n = w * 128 + nf * 16 + (lane & 15);
        float cs = 0.f;
        #pragma unroll
        for (int mf = 0; mf < 2; ++mf)
            #pragma unroll
            for (int r = 0; r < 4; ++r) {
                int row = mf * 16 + (lane >> 4) * 4 + r;
                float att = acc[mf][nf][r] * rcpden[mf][r];
                int byteoff = row * 1024 + ((((n >> 3) ^ row) & 63) << 4) + (n & 7) * 2;
                _Float16 hv = *((const _Float16*)&sA[byteoff]);
                cs += att * (float)hv;
            }
        cs += __shfl_xor(cs, 16);
        cs += __shfl_xor(cs, 32);
        if (lane < 16) atomicAdd(&out[b * 512 + n], cs);
    }
}

extern "C" void kernel_launch(void* const* d_in, const int* in_sizes, int n_in,
                              void* d_out, int out_size, void* d_ws, size_t ws_size,
                              hipStream_t stream) {
    const float* x    = (const float*)d_in[0];
    const int*   mask = (const int*)d_in[1];
    const float* W    = (const float*)d_in[2];
    const float* bias = (const float*)d_in[3];
    float* out = (float*)d_out;

    hipMemsetAsync(d_out, 0, (size_t)out_size * sizeof(float), stream);

    if (ws_size >= (size_t)524288) {
        uint4* wp = (uint4*)d_ws;
        pack_w_kernel<<<64, 256, 0, stream>>>(W, wp);
        attn_fused_kernel<1><<<2048, 256, 0, stream>>>(x, mask, W, wp, bias, out);
    } else {
        attn_fused_kernel<0><<<2048, 256, 0, stream>>>(x, mask, W, (const uint4*)nullptr, bias, out);
    }
}

// Round 6
// 316.072 us; speedup vs baseline: 2.3186x; 1.0920x over previous
//
#include <hip/hip_runtime.h>

typedef _Float16 half8 __attribute__((ext_vector_type(8)));
typedef float f32x4 __attribute__((ext_vector_type(4)));

#define LOG2E 1.44269504088896340736f

// B=64, T=512, S=1024. GEMM: [B*S, T] x [T, T], fused mask/tanh/softmax/reduce.

// async global->LDS, 16B per lane, dest = wave-uniform base + lane*16
__device__ __forceinline__ void gll16(const void* g, void* l) {
    __builtin_amdgcn_global_load_lds(
        (const __attribute__((address_space(1))) unsigned int*)g,
        (__attribute__((address_space(3))) unsigned int*)l,
        16, 0, 0);
}

// ---------------- W pack kernel (LDS-tiled, coalesced both sides) ----------------
// wp chunk c (16B) within ks-slab: n = c>>2, q = c&3, kb = q ^ (n&3),
//   elems j=0..7 -> W[ks*32 + kb*8 + j][n]
__global__ __launch_bounds__(256) void pack_w_kernel(const float* __restrict__ W,
                                                     uint4* __restrict__ wp) {
    __shared__ _Float16 sw[32][128];
    const int ks = blockIdx.x >> 2;        // 0..15
    const int nb = blockIdx.x & 3;         // 128-col group
    const int tid = threadIdx.x;
    #pragma unroll
    for (int rep = 0; rep < 16; ++rep) {
        int idx = rep * 256 + tid;         // 0..4095
        int k = idx >> 7, n = idx & 127;
        sw[k][n] = (_Float16)W[(size_t)(ks * 32 + k) * 512 + nb * 128 + n];
    }
    __syncthreads();
    #pragma unroll
    for (int rep = 0; rep < 2; ++rep) {
        int ci = rep * 256 + tid;          // local chunk 0..511
        int nloc = ci >> 2, q = ci & 3;
        int n = nb * 128 + nloc;
        int kb = q ^ (n & 3);
        union { _Float16 h[8]; uint4 u; } pk;
        #pragma unroll
        for (int j = 0; j < 8; ++j) pk.h[j] = sw[kb * 8 + j][nloc];
        wp[ks * 2048 + n * 4 + q] = pk.u;
    }
}

// ---------------- fused main kernel ----------------
// grid: 2048 blocks = 64 b * 32 s-tiles (32 rows each). 256 threads = 4 waves.
// LDS: sA = v-tile [32 m(s)][512 k(t)] f16 (XOR-swizzled chunks), built slab-by-slab
//      inside the K-loop (pipelined with MFMA); whole-K resident for the epilogue.
//      sW = W k-step tile (32k x 512n), staged via global_load_lds from packed image.
template <int USE_PACKED>
__global__ __launch_bounds__(256, 2)
void attn_fused_kernel(const float* __restrict__ x, const int* __restrict__ mask,
                       const float* __restrict__ Wraw, const uint4* __restrict__ wp4,
                       const float* __restrict__ bias, float* __restrict__ out) {
    __shared__ char sA[32768];
    __shared__ char sW[32768];

    const int tid  = threadIdx.x;
    const int lane = tid & 63;
    const int w    = tid >> 6;          // wave 0..3, owns n in [w*128, w*128+128)
    const int bid  = blockIdx.x;
    const int b    = bid >> 5;
    const int s0   = (bid & 31) * 32;
    const size_t xbase = (size_t)b * 512 * 1024;

    // A-slab assignment: per K-step ks, slab covers t in [ks*32, ks*32+32).
    // thread -> t = ks*32 + (tid>>3), m0 = (tid&7)*4; loads float4/int4 (coalesced),
    // writes 4 scalar f16 into swizzled sA: byte = m*1024 + ((((t>>3)^m)&63)<<4) + (t&7)*2
    const int tRow = tid >> 3;          // 0..31 within slab
    const int m0   = (tid & 7) * 4;

    f32x4 acc[2][8];
    #pragma unroll
    for (int i = 0; i < 2; ++i)
        #pragma unroll
        for (int j2 = 0; j2 < 8; ++j2)
            acc[i][j2] = (f32x4){0.f, 0.f, 0.f, 0.f};

    // prologue: issue A-loads for slab 0
    float4 ax;
    int4   am;
    {
        int t = tRow;
        size_t g = xbase + (size_t)t * 1024 + s0 + m0;
        ax = *reinterpret_cast<const float4*>(x + g);
        am = *reinterpret_cast<const int4*>(mask + g);
    }

    for (int ks = 0; ks < 16; ++ks) {
        __syncthreads();   // all waves done reading sW(ks-1); slab ks-1 writes visible
        // ---- issue W(ks) -> sW (async, L2-resident packed image) ----
        if constexpr (USE_PACKED) {
            const uint4* src = wp4 + ks * 2048 + w * 512 + lane;
            char* dst = &sW[w * 8192];
            #pragma unroll
            for (int c = 0; c < 8; ++c)
                gll16(src + c * 64, dst + c * 1024);
        } else {
            #pragma unroll 4
            for (int rep = 0; rep < 64; ++rep) {
                int id = rep * 256 + tid;
                int n = id & 511, kk = id >> 9;
                float wv = Wraw[(size_t)(ks * 32 + kk) * 512 + n];
                _Float16 h = (_Float16)wv;
                int byteoff = (n * 4 + ((kk >> 3) ^ (n & 3))) * 16 + (kk & 7) * 2;
                *((_Float16*)&sW[byteoff]) = h;
            }
        }
        // ---- convert+write A slab ks (regs loaded last iter; already drained) ----
        {
            int t = ks * 32 + tRow;
            float xs[4] = {ax.x, ax.y, ax.z, ax.w};
            int   ms[4] = {am.x, am.y, am.z, am.w};
            #pragma unroll
            for (int j = 0; j < 4; ++j) {
                float v = ms[j] ? xs[j] : 0.0f;
                _Float16 h = (_Float16)v;
                int m = m0 + j;
                int byteoff = m * 1024 + ((((t >> 3) ^ m) & 63) << 4) + (t & 7) * 2;
                *((_Float16*)&sA[byteoff]) = h;
            }
        }
        // ---- issue A-loads for slab ks+1 (land during MFMA phase) ----
        if (ks < 15) {
            int t = (ks + 1) * 32 + tRow;
            size_t g = xbase + (size_t)t * 1024 + s0 + m0;
            ax = *reinterpret_cast<const float4*>(x + g);
            am = *reinterpret_cast<const int4*>(mask + g);
        }
        __syncthreads();   // sW(ks) + slab ks ready (barrier drains counts)

        // A fragments: lane -> A[row = mf*16 + (lane&15)][k = ks*32 + (lane>>4)*8 + j]
        half8 aF[2];
        #pragma unroll
        for (int mf = 0; mf < 2; ++mf) {
            int mA = mf * 16 + (lane & 15);
            int byteoff = mA * 1024 + ((((ks * 4 + (lane >> 4)) ^ mA) & 63) << 4);
            aF[mf] = *((const half8*)&sA[byteoff]);
        }
        // B fragments + MFMA
        #pragma unroll
        for (int nf = 0; nf < 8; ++nf) {
            int n = w * 128 + nf * 16 + (lane & 15);
            int cchunk = n * 4 + ((lane >> 4) ^ (n & 3));
            half8 bF = *((const half8*)&sW[cchunk * 16]);
            acc[0][nf] = __builtin_amdgcn_mfma_f32_16x16x32_f16(aF[0], bF, acc[0][nf], 0, 0, 0);
            acc[1][nf] = __builtin_amdgcn_mfma_f32_16x16x32_f16(aF[1], bF, acc[1][nf], 0, 0, 0);
        }
    }

    // ---- Epilogue ----
    // acc[mf][nf][r] = z_pre[row = mf*16 + (lane>>4)*4 + r][n = w*128 + nf*16 + (lane&15)]
    float bb[8];
    #pragma unroll
    for (int nf = 0; nf < 8; ++nf)
        bb[nf] = bias[w * 128 + nf * 16 + (lane & 15)];

    float rs[2][4] = {};
    #pragma unroll
    for (int mf = 0; mf < 2; ++mf)
        #pragma unroll
        for (int nf = 0; nf < 8; ++nf)
            #pragma unroll
            for (int r = 0; r < 4; ++r) {
                float z = acc[mf][nf][r] + bb[nf];
                // tanh(z) = 1 - 2/(1+e^{2z}); saturates correctly at +/-inf
                float u = __builtin_amdgcn_exp2f(z * (2.0f * LOG2E));
                float t = 1.0f - 2.0f * __builtin_amdgcn_rcpf(1.0f + u);
                float e = __builtin_amdgcn_exp2f(t * LOG2E);
                acc[mf][nf][r] = e;
                rs[mf][r] += e;
            }
    // reduce e over the 16 col-lanes (same lane>>4 group)
    #pragma unroll
    for (int mf = 0; mf < 2; ++mf)
        #pragma unroll
        for (int r = 0; r < 4; ++r) {
            float v = rs[mf][r];
            v += __shfl_xor(v, 1);
            v += __shfl_xor(v, 2);
            v += __shfl_xor(v, 4);
            v += __shfl_xor(v, 8);
            rs[mf][r] = v;   // partial row-sum over this wave's 128 cols
        }
    __syncthreads();                  // all waves done reading sW -> reuse as scratch
    float* sc = (float*)sW;           // scratch [32 rows][4 waves]
    if ((lane & 15) == 0) {
        #pragma unroll
        for (int mf = 0; mf < 2; ++mf)
            #pragma unroll
            for (int r = 0; r < 4; ++r)
                sc[(mf * 16 + (lane >> 4) * 4 + r) * 4 + w] = rs[mf][r];
    }
    __syncthreads();
    float rcpden[2][4];
    #pragma unroll
    for (int mf = 0; mf < 2; ++mf)
        #pragma unroll
        for (int r = 0; r < 4; ++r) {
            int row = mf * 16 + (lane >> 4) * 4 + r;
            float d = sc[row * 4 + 0] + sc[row * 4 + 1] + sc[row * 4 + 2] + sc[row * 4 + 3] + 1e-7f;
            rcpden[mf][r] = __builtin_amdgcn_rcpf(d);
        }
    // out[b][n] += sum_rows att * v[row][n]   (v re-read from resident sA)
    #pragma unroll
    for (int nf = 0; nf < 8; ++nf) {
        int n = w * 128 + nf * 16 + (lane & 15);
        float cs = 0.f;
        #pragma unroll
        for (int mf = 0; mf < 2; ++mf)
            #pragma unroll
            for (int r = 0; r < 4; ++r) {
                int row = mf * 16 + (lane >> 4) * 4 + r;
                float att = acc[mf][nf][r] * rcpden[mf][r];
                int byteoff = row * 1024 + ((((n >> 3) ^ row) & 63) << 4) + (n & 7) * 2;
                _Float16 hv = *((const _Float16*)&sA[byteoff]);
                cs += att * (float)hv;
            }
        cs += __shfl_xor(cs, 16);
        cs += __shfl_xor(cs, 32);
        if (lane < 16) atomicAdd(&out[b * 512 + n], cs);
    }
}

extern "C" void kernel_launch(void* const* d_in, const int* in_sizes, int n_in,
                              void* d_out, int out_size, void* d_ws, size_t ws_size,
                              hipStream_t stream) {
    const float* x    = (const float*)d_in[0];
    const int*   mask = (const int*)d_in[1];
    const float* W    = (const float*)d_in[2];
    const float* bias = (const float*)d_in[3];
    float* out = (float*)d_out;

    hipMemsetAsync(d_out, 0, (size_t)out_size * sizeof(float), stream);

    if (ws_size >= (size_t)524288) {
        uint4* wp = (uint4*)d_ws;
        pack_w_kernel<<<64, 256, 0, stream>>>(W, wp);
        attn_fused_kernel<1><<<2048, 256, 0, stream>>>(x, mask, W, wp, bias, out);
    } else {
        attn_fused_kernel<0><<<2048, 256, 0, stream>>>(x, mask, W, (const uint4*)nullptr, bias, out);
    }
}